// Round 1
// baseline (187.819 us; speedup 1.0000x reference)
//
#include <hip/hip_runtime.h>
#include <math.h>

typedef unsigned short u16;
typedef __attribute__((ext_vector_type(8))) short short8;
typedef __attribute__((ext_vector_type(4))) float f32x4;
typedef __attribute__((ext_vector_type(4))) int i32x4;

__device__ inline u16 f2bf(float f){
  union { float f; unsigned int u; } x; x.f = f;
  unsigned int r = x.u + 0x7fffu + ((x.u >> 16) & 1u);
  return (u16)(r >> 16);
}

// ---------------- fp32 -> bf16 conversion ----------------
__global__ __launch_bounds__(256) void cvt_bf16(const float* __restrict__ in, u16* __restrict__ out, int n){
  int i = (blockIdx.x * 256 + threadIdx.x) * 4;
  if (i + 3 < n){
    float4 v = *(const float4*)(in + i);
    out[i]   = f2bf(v.x);
    out[i+1] = f2bf(v.y);
    out[i+2] = f2bf(v.z);
    out[i+3] = f2bf(v.w);
  }
}

// ---------------- LayerNorm (row=1024), fp32 in -> bf16 out ----------------
__global__ __launch_bounds__(256) void ln_kernel(const float* __restrict__ x, const float* __restrict__ g,
                                                 const float* __restrict__ b, u16* __restrict__ xn){
  const int row = blockIdx.x;
  const int tid = threadIdx.x;
  float4 v = *(const float4*)(x + (size_t)row*1024 + tid*4);
  float s  = v.x + v.y + v.z + v.w;
  float ss = v.x*v.x + v.y*v.y + v.z*v.z + v.w*v.w;
  #pragma unroll
  for (int off = 32; off; off >>= 1){
    s  += __shfl_xor(s,  off, 64);
    ss += __shfl_xor(ss, off, 64);
  }
  __shared__ float red[8];
  const int wid = tid >> 6;
  if ((tid & 63) == 0){ red[wid] = s; red[4+wid] = ss; }
  __syncthreads();
  float S  = red[0]+red[1]+red[2]+red[3];
  float SS = red[4]+red[5]+red[6]+red[7];
  float mu  = S * (1.0f/1024.0f);
  float var = SS * (1.0f/1024.0f) - mu*mu;
  float rs  = rsqrtf(var + 1e-5f);
  float4 gv = *(const float4*)(g + tid*4);
  float4 bv = *(const float4*)(b + tid*4);
  size_t o = (size_t)row*1024 + tid*4;
  xn[o]   = f2bf((v.x-mu)*rs*gv.x + bv.x);
  xn[o+1] = f2bf((v.y-mu)*rs*gv.y + bv.y);
  xn[o+2] = f2bf((v.z-mu)*rs*gv.z + bv.z);
  xn[o+3] = f2bf((v.w-mu)*rs*gv.w + bv.w);
}

// ---------------- GEMM: C[M,N] = A[M,K] * B[N,K]^T (+ epilogue) ----------------
// EPI 0: store bf16 only
// EPI 1: + resid(f32) -> store f32 AND bf16
// EPI 2: + bias -> exact GELU -> store bf16
// EPI 3: + bias + resid(f32) -> store f32
template<int EPI>
__global__ __launch_bounds__(256) void gemm_kernel(
    const u16* __restrict__ A, const u16* __restrict__ B,
    float* __restrict__ outF, u16* __restrict__ outB,
    const float* __restrict__ bias, const float* __restrict__ resid,
    int M, int N, int K)
{
  __shared__ u16 As[128][72];   // +8 pad: row stride 144B -> 2-way bank alias (free)
  __shared__ u16 Bs[128][72];
  const int tid = threadIdx.x;
  const int l   = tid & 63;
  const int w   = tid >> 6;
  const int wr  = w >> 1, wc = w & 1;
  const int brow = blockIdx.y, bcol = blockIdx.x;
  const int l15 = l & 15, l4 = l >> 4;

  f32x4 acc[4][4];
  #pragma unroll
  for (int i = 0; i < 4; ++i){
    #pragma unroll
    for (int j = 0; j < 4; ++j){
      acc[i][j] = (f32x4){0.f, 0.f, 0.f, 0.f};
    }
  }

  const int nkt = K >> 6;
  for (int kt = 0; kt < nkt; ++kt){
    #pragma unroll
    for (int i = 0; i < 4; ++i){
      int cid = tid + 256*i;         // 0..1023
      int r = cid >> 3, c = cid & 7;
      *(i32x4*)&As[r][c*8] = *(const i32x4*)(A + (size_t)(brow*128 + r)*K + kt*64 + c*8);
      *(i32x4*)&Bs[r][c*8] = *(const i32x4*)(B + (size_t)(bcol*128 + r)*K + kt*64 + c*8);
    }
    __syncthreads();
    #pragma unroll
    for (int ks = 0; ks < 2; ++ks){
      const int ko = ks*32 + l4*8;
      short8 af[4], bfr[4];
      #pragma unroll
      for (int i = 0; i < 4; ++i) af[i]  = *(const short8*)&As[wr*64 + i*16 + l15][ko];
      #pragma unroll
      for (int j = 0; j < 4; ++j) bfr[j] = *(const short8*)&Bs[wc*64 + j*16 + l15][ko];
      #pragma unroll
      for (int i = 0; i < 4; ++i){
        #pragma unroll
        for (int j = 0; j < 4; ++j){
          acc[i][j] = __builtin_amdgcn_mfma_f32_16x16x32_bf16(af[i], bfr[j], acc[i][j], 0, 0, 0);
        }
      }
    }
    __syncthreads();
  }

  #pragma unroll
  for (int i = 0; i < 4; ++i){
    #pragma unroll
    for (int j = 0; j < 4; ++j){
      #pragma unroll
      for (int r = 0; r < 4; ++r){
        int row = brow*128 + wr*64 + i*16 + l4*4 + r;
        int col = bcol*128 + wc*64 + j*16 + l15;
        float v = acc[i][j][r];
        size_t o = (size_t)row * N + col;
        if constexpr (EPI == 0){
          outB[o] = f2bf(v);
        } else if constexpr (EPI == 1){
          v += resid[o];
          outF[o] = v;
          outB[o] = f2bf(v);
        } else if constexpr (EPI == 2){
          v += bias[col];
          v = 0.5f * v * (1.0f + erff(v * 0.70710678118654752f));
          outB[o] = f2bf(v);
        } else {
          v += bias[col] + resid[o];
          outF[o] = v;
        }
      }
    }
  }
}

// ---------------- Local-window attention ----------------
// qkv: bf16 [2048, 3072] (cols: 0..1023 Q | 1024..2047 K | 2048..3071 V, per-head 64)
// block = (q-tile of 64, head). Band: keys q0-64 .. q0+127 (192), mask j in [qrl, qrl+128].
__global__ __launch_bounds__(256) void attn_kernel(const u16* __restrict__ qkv, u16* __restrict__ attn_out){
  constexpr int S = 2048, D3 = 3072;
  const int qt = blockIdx.x, h = blockIdx.y;
  const int q0 = qt * 64;
  const int tid = threadIdx.x;
  const int l = tid & 63, w = tid >> 6;
  const int l15 = l & 15, l4 = l >> 4;

  __shared__ u16 smem[31232];                    // 62464 B
  u16 (*Qs)[72]  = (u16(*)[72]) (smem);          // 64 x 72
  u16 (*Ks)[72]  = (u16(*)[72]) (smem + 4608);   // 192 x 72
  u16 (*Ps)[200] = (u16(*)[200])(smem + 4608);   // 64 x 200  (aliases Ks, after barrier)
  u16 (*Vt)[200] = (u16(*)[200])(smem + 18432);  // 64 x 200  (V transposed: [d][key])

  // stage Q (64 rows x 64)
  #pragma unroll
  for (int i = 0; i < 2; ++i){
    int cid = tid + 256*i; int r = cid >> 3, c = cid & 7;
    *(i32x4*)&Qs[r][c*8] = *(const i32x4*)(qkv + (size_t)(q0 + r)*D3 + h*64 + c*8);
  }
  // stage K (192 rows) and V transposed
  #pragma unroll
  for (int i = 0; i < 6; ++i){
    int cid = tid + 256*i; int r = cid >> 3, c = cid & 7;
    int kj = q0 - 64 + r;
    i32x4 kv = {0,0,0,0}, vv = {0,0,0,0};
    if (kj >= 0 && kj < S){
      kv = *(const i32x4*)(qkv + (size_t)kj*D3 + 1024 + h*64 + c*8);
      vv = *(const i32x4*)(qkv + (size_t)kj*D3 + 2048 + h*64 + c*8);
    }
    *(i32x4*)&Ks[r][c*8] = kv;
    union { i32x4 v; u16 u[8]; } uu; uu.v = vv;
    #pragma unroll
    for (int j = 0; j < 8; ++j) Vt[c*8 + j][r] = uu.u[j];
  }
  __syncthreads();

  // QK^T: wave w owns query rows [16w, 16w+16); 12 col-frags over 192 keys
  f32x4 sc[12];
  #pragma unroll
  for (int cf = 0; cf < 12; ++cf) sc[cf] = (f32x4){0.f,0.f,0.f,0.f};
  const int ko = l4 * 8;
  short8 a0 = *(const short8*)&Qs[16*w + l15][ko];
  short8 a1 = *(const short8*)&Qs[16*w + l15][32 + ko];
  #pragma unroll
  for (int cf = 0; cf < 12; ++cf){
    short8 b0 = *(const short8*)&Ks[cf*16 + l15][ko];
    short8 b1 = *(const short8*)&Ks[cf*16 + l15][32 + ko];
    sc[cf] = __builtin_amdgcn_mfma_f32_16x16x32_bf16(a0, b0, sc[cf], 0, 0, 0);
    sc[cf] = __builtin_amdgcn_mfma_f32_16x16x32_bf16(a1, b1, sc[cf], 0, 0, 0);
  }
  __syncthreads();   // everyone done reading Ks; Ps (alias) writable below

  const float scale = 0.125f;   // 1/sqrt(64)
  #pragma unroll
  for (int r = 0; r < 4; ++r){
    const int qrl = 16*w + l4*4 + r;       // query row within tile
    float mx = -1e30f;
    #pragma unroll
    for (int cf = 0; cf < 12; ++cf){
      int j  = cf*16 + l15;
      int kj = q0 - 64 + j;
      bool ok = (j >= qrl) && (j <= qrl + 128) && (kj >= 0) && (kj < S);
      float sv = ok ? sc[cf][r]*scale : -1e30f;
      sc[cf][r] = sv;
      mx = fmaxf(mx, sv);
    }
    #pragma unroll
    for (int off = 1; off < 16; off <<= 1) mx = fmaxf(mx, __shfl_xor(mx, off, 64));
    float sm = 0.f;
    #pragma unroll
    for (int cf = 0; cf < 12; ++cf){
      float pv = __expf(sc[cf][r] - mx);
      sc[cf][r] = pv;
      sm += pv;
    }
    #pragma unroll
    for (int off = 1; off < 16; off <<= 1) sm += __shfl_xor(sm, off, 64);
    float inv = 1.0f / sm;
    #pragma unroll
    for (int cf = 0; cf < 12; ++cf) Ps[qrl][cf*16 + l15] = f2bf(sc[cf][r] * inv);
  }
  __syncthreads();

  // PV: out[64q x 64d] ; A = P rows, B = Vt rows (contiguous k)
  f32x4 o[4];
  #pragma unroll
  for (int df = 0; df < 4; ++df) o[df] = (f32x4){0.f,0.f,0.f,0.f};
  #pragma unroll
  for (int kk = 0; kk < 6; ++kk){
    short8 a = *(const short8*)&Ps[16*w + l15][kk*32 + ko];
    #pragma unroll
    for (int df = 0; df < 4; ++df){
      short8 b = *(const short8*)&Vt[df*16 + l15][kk*32 + ko];
      o[df] = __builtin_amdgcn_mfma_f32_16x16x32_bf16(a, b, o[df], 0, 0, 0);
    }
  }
  #pragma unroll
  for (int df = 0; df < 4; ++df){
    #pragma unroll
    for (int r = 0; r < 4; ++r){
      attn_out[(size_t)(q0 + 16*w + l4*4 + r)*1024 + h*64 + df*16 + l15] = f2bf(o[df][r]);
    }
  }
}

extern "C" void kernel_launch(void* const* d_in, const int* in_sizes, int n_in,
                              void* d_out, int out_size, void* d_ws, size_t ws_size,
                              hipStream_t stream)
{
  const float* x     = (const float*)d_in[0];
  const float* qkv_w = (const float*)d_in[1];
  const float* out_w = (const float*)d_in[2];
  const float* ln_g  = (const float*)d_in[3];
  const float* ln_b  = (const float*)d_in[4];
  const float* w1    = (const float*)d_in[5];
  const float* b1    = (const float*)d_in[6];
  const float* w2    = (const float*)d_in[7];
  const float* b2    = (const float*)d_in[8];
  float* out_final = (float*)d_out;

  char* p = (char*)d_ws;
  u16* qkvw_b = (u16*)p; p += (size_t)3072*1024*2;
  u16* outw_b = (u16*)p; p += (size_t)1024*1024*2;
  u16* w1_b   = (u16*)p; p += (size_t)4096*1024*2;
  u16* w2_b   = (u16*)p; p += (size_t)1024*4096*2;
  u16* xn_b   = (u16*)p; p += (size_t)2048*1024*2;
  u16* qkv_b  = (u16*)p; p += (size_t)2048*3072*2;
  u16* attn_b = (u16*)p; p += (size_t)2048*1024*2;
  float* out_f= (float*)p; p += (size_t)2048*1024*4;
  u16* out_b  = (u16*)p; p += (size_t)2048*1024*2;
  u16* h_b    = (u16*)p; p += (size_t)2048*4096*2;

  // weight conversion
  cvt_bf16<<<3072, 256, 0, stream>>>(qkv_w, qkvw_b, 3072*1024);
  cvt_bf16<<<1024, 256, 0, stream>>>(out_w, outw_b, 1024*1024);
  cvt_bf16<<<4096, 256, 0, stream>>>(w1,    w1_b,   4096*1024);
  cvt_bf16<<<4096, 256, 0, stream>>>(w2,    w2_b,   1024*4096);
  // LayerNorm
  ln_kernel<<<2048, 256, 0, stream>>>(x, ln_g, ln_b, xn_b);
  // QKV projection: [2048,1024] x [3072,1024]^T -> bf16 [2048,3072]
  gemm_kernel<0><<<dim3(24,16), 256, 0, stream>>>(xn_b, qkvw_b, nullptr, qkv_b, nullptr, nullptr, 2048, 3072, 1024);
  // local attention -> bf16 [2048,1024]
  attn_kernel<<<dim3(32,16), 256, 0, stream>>>(qkv_b, attn_b);
  // out projection + residual(x): -> out_f32 + out_bf16
  gemm_kernel<1><<<dim3(8,16), 256, 0, stream>>>(attn_b, outw_b, out_f, out_b, nullptr, x, 2048, 1024, 1024);
  // FFN1 + bias + exact GELU -> h bf16 [2048,4096]
  gemm_kernel<2><<<dim3(32,16), 256, 0, stream>>>(out_b, w1_b, nullptr, h_b, b1, nullptr, 2048, 4096, 1024);
  // FFN2 + bias + residual(out_f) -> final f32
  gemm_kernel<3><<<dim3(8,16), 256, 0, stream>>>(h_b, w2_b, out_final, nullptr, b2, out_f, 2048, 1024, 4096);
}

// Round 2
// 175.433 us; speedup vs baseline: 1.0706x; 1.0706x over previous
//
#include <hip/hip_runtime.h>
#include <math.h>

typedef unsigned short u16;
typedef __attribute__((ext_vector_type(8))) short short8;
typedef __attribute__((ext_vector_type(4))) float f32x4;
typedef __attribute__((ext_vector_type(4))) int i32x4;

__device__ inline u16 f2bf(float f){
  union { float f; unsigned int u; } x; x.f = f;
  unsigned int r = x.u + 0x7fffu + ((x.u >> 16) & 1u);
  return (u16)(r >> 16);
}

// ---------------- fp32 -> bf16 conversion ----------------
__global__ __launch_bounds__(256) void cvt_bf16(const float* __restrict__ in, u16* __restrict__ out, int n){
  int i = (blockIdx.x * 256 + threadIdx.x) * 4;
  if (i + 3 < n){
    float4 v = *(const float4*)(in + i);
    out[i]   = f2bf(v.x);
    out[i+1] = f2bf(v.y);
    out[i+2] = f2bf(v.z);
    out[i+3] = f2bf(v.w);
  }
}

// ---------------- LayerNorm (row=1024), fp32 in -> bf16 out ----------------
__global__ __launch_bounds__(256) void ln_kernel(const float* __restrict__ x, const float* __restrict__ g,
                                                 const float* __restrict__ b, u16* __restrict__ xn){
  const int row = blockIdx.x;
  const int tid = threadIdx.x;
  float4 v = *(const float4*)(x + (size_t)row*1024 + tid*4);
  float s  = v.x + v.y + v.z + v.w;
  float ss = v.x*v.x + v.y*v.y + v.z*v.z + v.w*v.w;
  #pragma unroll
  for (int off = 32; off; off >>= 1){
    s  += __shfl_xor(s,  off, 64);
    ss += __shfl_xor(ss, off, 64);
  }
  __shared__ float red[8];
  const int wid = tid >> 6;
  if ((tid & 63) == 0){ red[wid] = s; red[4+wid] = ss; }
  __syncthreads();
  float S  = red[0]+red[1]+red[2]+red[3];
  float SS = red[4]+red[5]+red[6]+red[7];
  float mu  = S * (1.0f/1024.0f);
  float var = SS * (1.0f/1024.0f) - mu*mu;
  float rs  = rsqrtf(var + 1e-5f);
  float4 gv = *(const float4*)(g + tid*4);
  float4 bv = *(const float4*)(b + tid*4);
  size_t o = (size_t)row*1024 + tid*4;
  xn[o]   = f2bf((v.x-mu)*rs*gv.x + bv.x);
  xn[o+1] = f2bf((v.y-mu)*rs*gv.y + bv.y);
  xn[o+2] = f2bf((v.z-mu)*rs*gv.z + bv.z);
  xn[o+3] = f2bf((v.w-mu)*rs*gv.w + bv.w);
}

// ---------------- GEMM (m97 structure): C[M,N] = A[M,K] * B[N,K]^T ----------------
// Staging via global_load_lds width=16, linear LDS [128][64] bf16 (no pad).
// EPI 0: store bf16 only
// EPI 1: + resid(f32) -> store f32 AND bf16
// EPI 2: + bias -> exact GELU -> store bf16
// EPI 4: partial f32 (split-K), outF offset by blockIdx.z*M*N
template<int EPI>
__global__ __launch_bounds__(256) void gemm_lds(
    const u16* __restrict__ A, const u16* __restrict__ B,
    float* __restrict__ outF, u16* __restrict__ outB,
    const float* __restrict__ bias, const float* __restrict__ resid,
    int M, int N, int K, int splitk)
{
  __shared__ u16 As[128*64];
  __shared__ u16 Bs[128*64];
  const int tid = threadIdx.x;
  const int l   = tid & 63;
  const int w   = tid >> 6;
  const int wr  = w >> 1, wc = w & 1;
  const int bcol = blockIdx.x, brow = blockIdx.y, kz = blockIdx.z;
  const int l15 = l & 15, l4 = l >> 4;
  const int Kc = K / splitk;

  const u16* Ab = A + (size_t)brow*128*K + (size_t)kz*Kc;
  const u16* Bb = B + (size_t)bcol*128*K + (size_t)kz*Kc;

  f32x4 acc[4][4];
  #pragma unroll
  for (int i = 0; i < 4; ++i)
    #pragma unroll
    for (int j = 0; j < 4; ++j)
      acc[i][j] = (f32x4){0.f, 0.f, 0.f, 0.f};

  const int rsub = l >> 3;          // 0..7
  const int csub = (l & 7) * 8;     // element col within 64
  const int nkt = Kc >> 6;
  for (int kt = 0; kt < nkt; ++kt){
    const u16* Ag = Ab + kt*64;
    const u16* Bg = Bb + kt*64;
    #pragma unroll
    for (int i = 0; i < 4; ++i){
      const int chunk = w*4 + i;              // 0..15, wave-uniform
      const int r = chunk*8 + rsub;           // row 0..127
      __builtin_amdgcn_global_load_lds(
        (const __attribute__((address_space(1))) void*)(Ag + (size_t)r*K + csub),
        (__attribute__((address_space(3))) void*)(As + chunk*512), 16, 0, 0);
      __builtin_amdgcn_global_load_lds(
        (const __attribute__((address_space(1))) void*)(Bg + (size_t)r*K + csub),
        (__attribute__((address_space(3))) void*)(Bs + chunk*512), 16, 0, 0);
    }
    __syncthreads();                           // drains vmcnt -> tiles ready
    #pragma unroll
    for (int ks = 0; ks < 2; ++ks){
      const int ko = ks*32 + l4*8;
      short8 af[4], bfr[4];
      #pragma unroll
      for (int i = 0; i < 4; ++i) af[i]  = *(const short8*)&As[(wr*64 + i*16 + l15)*64 + ko];
      #pragma unroll
      for (int j = 0; j < 4; ++j) bfr[j] = *(const short8*)&Bs[(wc*64 + j*16 + l15)*64 + ko];
      #pragma unroll
      for (int i = 0; i < 4; ++i)
        #pragma unroll
        for (int j = 0; j < 4; ++j)
          acc[i][j] = __builtin_amdgcn_mfma_f32_16x16x32_bf16(af[i], bfr[j], acc[i][j], 0, 0, 0);
    }
    __syncthreads();
  }

  #pragma unroll
  for (int i = 0; i < 4; ++i){
    #pragma unroll
    for (int j = 0; j < 4; ++j){
      #pragma unroll
      for (int r = 0; r < 4; ++r){
        int row = brow*128 + wr*64 + i*16 + l4*4 + r;
        int col = bcol*128 + wc*64 + j*16 + l15;
        float v = acc[i][j][r];
        size_t o = (size_t)row * N + col;
        if constexpr (EPI == 0){
          outB[o] = f2bf(v);
        } else if constexpr (EPI == 1){
          v += resid[o];
          outF[o] = v;
          outB[o] = f2bf(v);
        } else if constexpr (EPI == 2){
          v += bias[col];
          v = 0.5f * v * (1.0f + erff(v * 0.70710678118654752f));
          outB[o] = f2bf(v);
        } else {  // EPI == 4: split-K partial
          outF[(size_t)kz * M * N + o] = v;
        }
      }
    }
  }
}

// ---------------- FFN2 split-K reduce: out = p0 + p1 + bias + resid ----------------
__global__ __launch_bounds__(256) void reduce_ffn2(const float* __restrict__ p,
                                                   const float* __restrict__ bias,
                                                   const float* __restrict__ resid,
                                                   float* __restrict__ out){
  const int i = (blockIdx.x * 256 + threadIdx.x) * 4;
  float4 a = *(const float4*)(p + i);
  float4 b = *(const float4*)(p + (size_t)2048*1024 + i);
  float4 r = *(const float4*)(resid + i);
  float4 bb = *(const float4*)(bias + (i & 1023));
  float4 o;
  o.x = a.x + b.x + r.x + bb.x;
  o.y = a.y + b.y + r.y + bb.y;
  o.z = a.z + b.z + r.z + bb.z;
  o.w = a.w + b.w + r.w + bb.w;
  *(float4*)(out + i) = o;
}

// ---------------- Local-window attention ----------------
__global__ __launch_bounds__(256) void attn_kernel(const u16* __restrict__ qkv, u16* __restrict__ attn_out){
  constexpr int S = 2048, D3 = 3072;
  const int qt = blockIdx.x, h = blockIdx.y;
  const int q0 = qt * 64;
  const int tid = threadIdx.x;
  const int l = tid & 63, w = tid >> 6;
  const int l15 = l & 15, l4 = l >> 4;

  __shared__ u16 smem[31232];                    // 62464 B
  u16 (*Qs)[72]  = (u16(*)[72]) (smem);          // 64 x 72
  u16 (*Ks)[72]  = (u16(*)[72]) (smem + 4608);   // 192 x 72
  u16 (*Ps)[200] = (u16(*)[200])(smem + 4608);   // 64 x 200  (aliases Ks, after barrier)
  u16 (*Vt)[200] = (u16(*)[200])(smem + 18432);  // 64 x 200  (V transposed: [d][key])

  #pragma unroll
  for (int i = 0; i < 2; ++i){
    int cid = tid + 256*i; int r = cid >> 3, c = cid & 7;
    *(i32x4*)&Qs[r][c*8] = *(const i32x4*)(qkv + (size_t)(q0 + r)*D3 + h*64 + c*8);
  }
  #pragma unroll
  for (int i = 0; i < 6; ++i){
    int cid = tid + 256*i; int r = cid >> 3, c = cid & 7;
    int kj = q0 - 64 + r;
    i32x4 kv = {0,0,0,0}, vv = {0,0,0,0};
    if (kj >= 0 && kj < S){
      kv = *(const i32x4*)(qkv + (size_t)kj*D3 + 1024 + h*64 + c*8);
      vv = *(const i32x4*)(qkv + (size_t)kj*D3 + 2048 + h*64 + c*8);
    }
    *(i32x4*)&Ks[r][c*8] = kv;
    union { i32x4 v; u16 u[8]; } uu; uu.v = vv;
    #pragma unroll
    for (int j = 0; j < 8; ++j) Vt[c*8 + j][r] = uu.u[j];
  }
  __syncthreads();

  f32x4 sc[12];
  #pragma unroll
  for (int cf = 0; cf < 12; ++cf) sc[cf] = (f32x4){0.f,0.f,0.f,0.f};
  const int ko = l4 * 8;
  short8 a0 = *(const short8*)&Qs[16*w + l15][ko];
  short8 a1 = *(const short8*)&Qs[16*w + l15][32 + ko];
  #pragma unroll
  for (int cf = 0; cf < 12; ++cf){
    short8 b0 = *(const short8*)&Ks[cf*16 + l15][ko];
    short8 b1 = *(const short8*)&Ks[cf*16 + l15][32 + ko];
    sc[cf] = __builtin_amdgcn_mfma_f32_16x16x32_bf16(a0, b0, sc[cf], 0, 0, 0);
    sc[cf] = __builtin_amdgcn_mfma_f32_16x16x32_bf16(a1, b1, sc[cf], 0, 0, 0);
  }
  __syncthreads();

  const float scale = 0.125f;
  #pragma unroll
  for (int r = 0; r < 4; ++r){
    const int qrl = 16*w + l4*4 + r;
    float mx = -1e30f;
    #pragma unroll
    for (int cf = 0; cf < 12; ++cf){
      int j  = cf*16 + l15;
      int kj = q0 - 64 + j;
      bool ok = (j >= qrl) && (j <= qrl + 128) && (kj >= 0) && (kj < S);
      float sv = ok ? sc[cf][r]*scale : -1e30f;
      sc[cf][r] = sv;
      mx = fmaxf(mx, sv);
    }
    #pragma unroll
    for (int off = 1; off < 16; off <<= 1) mx = fmaxf(mx, __shfl_xor(mx, off, 64));
    float sm = 0.f;
    #pragma unroll
    for (int cf = 0; cf < 12; ++cf){
      float pv = __expf(sc[cf][r] - mx);
      sc[cf][r] = pv;
      sm += pv;
    }
    #pragma unroll
    for (int off = 1; off < 16; off <<= 1) sm += __shfl_xor(sm, off, 64);
    float inv = 1.0f / sm;
    #pragma unroll
    for (int cf = 0; cf < 12; ++cf) Ps[qrl][cf*16 + l15] = f2bf(sc[cf][r] * inv);
  }
  __syncthreads();

  f32x4 o[4];
  #pragma unroll
  for (int df = 0; df < 4; ++df) o[df] = (f32x4){0.f,0.f,0.f,0.f};
  #pragma unroll
  for (int kk = 0; kk < 6; ++kk){
    short8 a = *(const short8*)&Ps[16*w + l15][kk*32 + ko];
    #pragma unroll
    for (int df = 0; df < 4; ++df){
      short8 b = *(const short8*)&Vt[df*16 + l15][kk*32 + ko];
      o[df] = __builtin_amdgcn_mfma_f32_16x16x32_bf16(a, b, o[df], 0, 0, 0);
    }
  }
  #pragma unroll
  for (int df = 0; df < 4; ++df){
    #pragma unroll
    for (int r = 0; r < 4; ++r){
      attn_out[(size_t)(q0 + 16*w + l4*4 + r)*1024 + h*64 + df*16 + l15] = f2bf(o[df][r]);
    }
  }
}

extern "C" void kernel_launch(void* const* d_in, const int* in_sizes, int n_in,
                              void* d_out, int out_size, void* d_ws, size_t ws_size,
                              hipStream_t stream)
{
  const float* x     = (const float*)d_in[0];
  const float* qkv_w = (const float*)d_in[1];
  const float* out_w = (const float*)d_in[2];
  const float* ln_g  = (const float*)d_in[3];
  const float* ln_b  = (const float*)d_in[4];
  const float* w1    = (const float*)d_in[5];
  const float* b1    = (const float*)d_in[6];
  const float* w2    = (const float*)d_in[7];
  const float* b2    = (const float*)d_in[8];
  float* out_final = (float*)d_out;

  char* p = (char*)d_ws;
  u16* qkvw_b = (u16*)p; p += (size_t)3072*1024*2;
  u16* outw_b = (u16*)p; p += (size_t)1024*1024*2;
  u16* w1_b   = (u16*)p; p += (size_t)4096*1024*2;
  u16* w2_b   = (u16*)p; p += (size_t)1024*4096*2;
  u16* xn_b   = (u16*)p; p += (size_t)2048*1024*2;   // dead after QKV -> reused for partials
  u16* qkv_b  = (u16*)p; p += (size_t)2048*3072*2;   // dead after attn -> reused for partials
  u16* attn_b = (u16*)p; p += (size_t)2048*1024*2;   // dead after out-proj
  float* out_f= (float*)p; p += (size_t)2048*1024*4; // live until reduce
  u16* out_b  = (u16*)p; p += (size_t)2048*1024*2;   // dead after FFN1
  u16* h_b    = (u16*)p; p += (size_t)2048*4096*2;

  float* partials = (float*)xn_b;  // 2 x 2048x1024 f32 = 16.78 MB over xn_b+qkv_b (both dead by FFN2)

  // weight conversion
  cvt_bf16<<<3072, 256, 0, stream>>>(qkv_w, qkvw_b, 3072*1024);
  cvt_bf16<<<1024, 256, 0, stream>>>(out_w, outw_b, 1024*1024);
  cvt_bf16<<<4096, 256, 0, stream>>>(w1,    w1_b,   4096*1024);
  cvt_bf16<<<4096, 256, 0, stream>>>(w2,    w2_b,   1024*4096);
  // LayerNorm
  ln_kernel<<<2048, 256, 0, stream>>>(x, ln_g, ln_b, xn_b);
  // QKV projection: [2048,1024] x [3072,1024]^T -> bf16 [2048,3072]
  gemm_lds<0><<<dim3(24,16), 256, 0, stream>>>(xn_b, qkvw_b, nullptr, qkv_b, nullptr, nullptr, 2048, 3072, 1024, 1);
  // local attention -> bf16 [2048,1024]
  attn_kernel<<<dim3(32,16), 256, 0, stream>>>(qkv_b, attn_b);
  // out projection + residual(x): -> out_f32 + out_bf16
  gemm_lds<1><<<dim3(8,16), 256, 0, stream>>>(attn_b, outw_b, out_f, out_b, nullptr, x, 2048, 1024, 1024, 1);
  // FFN1 + bias + exact GELU -> h bf16 [2048,4096]
  gemm_lds<2><<<dim3(32,16), 256, 0, stream>>>(out_b, w1_b, nullptr, h_b, b1, nullptr, 2048, 4096, 1024, 1);
  // FFN2 split-K=2 partials -> f32
  gemm_lds<4><<<dim3(8,16,2), 256, 0, stream>>>(h_b, w2_b, partials, nullptr, nullptr, nullptr, 2048, 1024, 4096, 2);
  // reduce: out = p0 + p1 + b2 + out_f
  reduce_ffn2<<<2048, 256, 0, stream>>>(partials, b2, out_f, out_final);
}

// Round 3
// 139.494 us; speedup vs baseline: 1.3464x; 1.2576x over previous
//
#include <hip/hip_runtime.h>
#include <math.h>

typedef unsigned short u16;
typedef __attribute__((ext_vector_type(8))) short short8;
typedef __attribute__((ext_vector_type(4))) float f32x4;
typedef __attribute__((ext_vector_type(4))) int i32x4;

__device__ inline u16 f2bf(float f){
  union { float f; unsigned int u; } x; x.f = f;
  unsigned int r = x.u + 0x7fffu + ((x.u >> 16) & 1u);
  return (u16)(r >> 16);
}

// ---------------- fp32 -> bf16 conversion ----------------
__global__ __launch_bounds__(256) void cvt_bf16(const float* __restrict__ in, u16* __restrict__ out, int n){
  int i = (blockIdx.x * 256 + threadIdx.x) * 4;
  if (i + 3 < n){
    float4 v = *(const float4*)(in + i);
    out[i]   = f2bf(v.x);
    out[i+1] = f2bf(v.y);
    out[i+2] = f2bf(v.z);
    out[i+3] = f2bf(v.w);
  }
}

// ---------------- LayerNorm (row=1024), fp32 in -> bf16 out ----------------
__global__ __launch_bounds__(256) void ln_kernel(const float* __restrict__ x, const float* __restrict__ g,
                                                 const float* __restrict__ b, u16* __restrict__ xn){
  const int row = blockIdx.x;
  const int tid = threadIdx.x;
  float4 v = *(const float4*)(x + (size_t)row*1024 + tid*4);
  float s  = v.x + v.y + v.z + v.w;
  float ss = v.x*v.x + v.y*v.y + v.z*v.z + v.w*v.w;
  #pragma unroll
  for (int off = 32; off; off >>= 1){
    s  += __shfl_xor(s,  off, 64);
    ss += __shfl_xor(ss, off, 64);
  }
  __shared__ float red[8];
  const int wid = tid >> 6;
  if ((tid & 63) == 0){ red[wid] = s; red[4+wid] = ss; }
  __syncthreads();
  float S  = red[0]+red[1]+red[2]+red[3];
  float SS = red[4]+red[5]+red[6]+red[7];
  float mu  = S * (1.0f/1024.0f);
  float var = SS * (1.0f/1024.0f) - mu*mu;
  float rs  = rsqrtf(var + 1e-5f);
  float4 gv = *(const float4*)(g + tid*4);
  float4 bv = *(const float4*)(b + tid*4);
  size_t o = (size_t)row*1024 + tid*4;
  xn[o]   = f2bf((v.x-mu)*rs*gv.x + bv.x);
  xn[o+1] = f2bf((v.y-mu)*rs*gv.y + bv.y);
  xn[o+2] = f2bf((v.z-mu)*rs*gv.z + bv.z);
  xn[o+3] = f2bf((v.w-mu)*rs*gv.w + bv.w);
}

// ---------------- GEMM 128x64 tile: C[M,N] = A[M,K] * B[N,K]^T ----------------
// global_load_lds width=16, linear LDS dest, T2 bank-swizzle via pre-swizzled
// global SOURCE col (row&7): LDS[row][c] = G[row][c ^ (row&7)*8].
// 4 waves 2x2; wave tile 64(M) x 32(N); acc 4x2 frags of 16x16.
// EPI 0: store bf16 | EPI 1: +resid -> f32+bf16 | EPI 2: +bias,GELU -> bf16
// EPI 4: split-K partial f32 at outF + kz*M*N
template<int EPI>
__global__ __launch_bounds__(256) void gemm_lds(
    const u16* __restrict__ A, const u16* __restrict__ B,
    float* __restrict__ outF, u16* __restrict__ outB,
    const float* __restrict__ bias, const float* __restrict__ resid,
    int M, int N, int K, int nbx, int nwg, int Kc)
{
  __shared__ u16 As[128*64];
  __shared__ u16 Bs[64*64];
  const int tid = threadIdx.x;
  const int l   = tid & 63;
  const int w   = tid >> 6;
  const int wr  = w >> 1, wc = w & 1;
  const int orig = blockIdx.x;
  const int wgid = (orig & 7) * (nwg >> 3) + (orig >> 3);   // XCD-contiguous (nwg%8==0)
  const int bcol = wgid % nbx, brow = wgid / nbx;
  const int kz = blockIdx.y;
  const int l15 = l & 15, l4 = l >> 4;

  const u16* Ab = A + (size_t)brow*128*K + (size_t)kz*Kc;
  const u16* Bb = B + (size_t)bcol*64*K  + (size_t)kz*Kc;

  f32x4 acc[4][2];
  #pragma unroll
  for (int i = 0; i < 4; ++i)
    #pragma unroll
    for (int j = 0; j < 2; ++j)
      acc[i][j] = (f32x4){0.f, 0.f, 0.f, 0.f};

  const int rsub = l >> 3;                       // 0..7 (== row & 7 of this lane's slot)
  const int csrc = ((l & 7) ^ rsub) * 8;         // swizzled source col (elements)
  const int swz  = (l15 & 7) * 8;                // read-side unswizzle
  const int nkt = Kc >> 6;
  for (int kt = 0; kt < nkt; ++kt){
    const u16* Ag = Ab + kt*64 + csrc;
    const u16* Bg = Bb + kt*64 + csrc;
    #pragma unroll
    for (int i = 0; i < 4; ++i){
      const int ca = w*4 + i;                    // A chunk 0..15 (8 rows x 64 cols)
      __builtin_amdgcn_global_load_lds(
        (const __attribute__((address_space(1))) void*)(Ag + (size_t)(ca*8 + rsub)*K),
        (__attribute__((address_space(3))) void*)(As + ca*512), 16, 0, 0);
    }
    #pragma unroll
    for (int i = 0; i < 2; ++i){
      const int cb = w*2 + i;                    // B chunk 0..7
      __builtin_amdgcn_global_load_lds(
        (const __attribute__((address_space(1))) void*)(Bg + (size_t)(cb*8 + rsub)*K),
        (__attribute__((address_space(3))) void*)(Bs + cb*512), 16, 0, 0);
    }
    __syncthreads();                             // drains vmcnt -> tiles ready
    #pragma unroll
    for (int ks = 0; ks < 2; ++ks){
      const int kop = (ks*32 + l4*8) ^ swz;
      short8 af[4], bfr[2];
      #pragma unroll
      for (int i = 0; i < 4; ++i) af[i]  = *(const short8*)&As[(wr*64 + i*16 + l15)*64 + kop];
      #pragma unroll
      for (int j = 0; j < 2; ++j) bfr[j] = *(const short8*)&Bs[(wc*32 + j*16 + l15)*64 + kop];
      #pragma unroll
      for (int i = 0; i < 4; ++i)
        #pragma unroll
        for (int j = 0; j < 2; ++j)
          acc[i][j] = __builtin_amdgcn_mfma_f32_16x16x32_bf16(af[i], bfr[j], acc[i][j], 0, 0, 0);
    }
    __syncthreads();
  }

  #pragma unroll
  for (int i = 0; i < 4; ++i){
    #pragma unroll
    for (int j = 0; j < 2; ++j){
      #pragma unroll
      for (int r = 0; r < 4; ++r){
        int row = brow*128 + wr*64 + i*16 + l4*4 + r;
        int col = bcol*64 + wc*32 + j*16 + l15;
        float v = acc[i][j][r];
        size_t o = (size_t)row * N + col;
        if constexpr (EPI == 0){
          outB[o] = f2bf(v);
        } else if constexpr (EPI == 1){
          v += resid[o];
          outF[o] = v;
          outB[o] = f2bf(v);
        } else if constexpr (EPI == 2){
          v += bias[col];
          v = 0.5f * v * (1.0f + erff(v * 0.70710678118654752f));
          outB[o] = f2bf(v);
        } else {  // EPI == 4: split-K partial
          outF[(size_t)kz * M * N + o] = v;
        }
      }
    }
  }
}

// ---------------- FFN2 split-K=4 reduce: out = p0+p1+p2+p3 + bias + resid ----------------
__global__ __launch_bounds__(256) void reduce_ffn2(const float* __restrict__ p,
                                                   const float* __restrict__ bias,
                                                   const float* __restrict__ resid,
                                                   float* __restrict__ out){
  const size_t s = (size_t)2048*1024;
  const size_t i = ((size_t)blockIdx.x * 256 + threadIdx.x) * 4;
  float4 a0 = *(const float4*)(p + i);
  float4 a1 = *(const float4*)(p + s + i);
  float4 a2 = *(const float4*)(p + 2*s + i);
  float4 a3 = *(const float4*)(p + 3*s + i);
  float4 r  = *(const float4*)(resid + i);
  float4 bb = *(const float4*)(bias + (i & 1023));
  float4 o;
  o.x = a0.x + a1.x + a2.x + a3.x + r.x + bb.x;
  o.y = a0.y + a1.y + a2.y + a3.y + r.y + bb.y;
  o.z = a0.z + a1.z + a2.z + a3.z + r.z + bb.z;
  o.w = a0.w + a1.w + a2.w + a3.w + r.w + bb.w;
  *(float4*)(out + i) = o;
}

// ---------------- Local-window attention ----------------
__global__ __launch_bounds__(256) void attn_kernel(const u16* __restrict__ qkv, u16* __restrict__ attn_out){
  constexpr int S = 2048, D3 = 3072;
  const int qt = blockIdx.x, h = blockIdx.y;
  const int q0 = qt * 64;
  const int tid = threadIdx.x;
  const int l = tid & 63, w = tid >> 6;
  const int l15 = l & 15, l4 = l >> 4;

  __shared__ u16 smem[31232];                    // 62464 B
  u16 (*Qs)[72]  = (u16(*)[72]) (smem);          // 64 x 72
  u16 (*Ks)[72]  = (u16(*)[72]) (smem + 4608);   // 192 x 72
  u16 (*Ps)[200] = (u16(*)[200])(smem + 4608);   // 64 x 200  (aliases Ks, after barrier)
  u16 (*Vt)[200] = (u16(*)[200])(smem + 18432);  // 64 x 200  (V transposed: [d][key])

  #pragma unroll
  for (int i = 0; i < 2; ++i){
    int cid = tid + 256*i; int r = cid >> 3, c = cid & 7;
    *(i32x4*)&Qs[r][c*8] = *(const i32x4*)(qkv + (size_t)(q0 + r)*D3 + h*64 + c*8);
  }
  #pragma unroll
  for (int i = 0; i < 6; ++i){
    int cid = tid + 256*i; int r = cid >> 3, c = cid & 7;
    int kj = q0 - 64 + r;
    i32x4 kv = {0,0,0,0}, vv = {0,0,0,0};
    if (kj >= 0 && kj < S){
      kv = *(const i32x4*)(qkv + (size_t)kj*D3 + 1024 + h*64 + c*8);
      vv = *(const i32x4*)(qkv + (size_t)kj*D3 + 2048 + h*64 + c*8);
    }
    *(i32x4*)&Ks[r][c*8] = kv;
    union { i32x4 v; u16 u[8]; } uu; uu.v = vv;
    #pragma unroll
    for (int j = 0; j < 8; ++j) Vt[c*8 + j][r] = uu.u[j];
  }
  __syncthreads();

  f32x4 sc[12];
  #pragma unroll
  for (int cf = 0; cf < 12; ++cf) sc[cf] = (f32x4){0.f,0.f,0.f,0.f};
  const int ko = l4 * 8;
  short8 a0 = *(const short8*)&Qs[16*w + l15][ko];
  short8 a1 = *(const short8*)&Qs[16*w + l15][32 + ko];
  #pragma unroll
  for (int cf = 0; cf < 12; ++cf){
    short8 b0 = *(const short8*)&Ks[cf*16 + l15][ko];
    short8 b1 = *(const short8*)&Ks[cf*16 + l15][32 + ko];
    sc[cf] = __builtin_amdgcn_mfma_f32_16x16x32_bf16(a0, b0, sc[cf], 0, 0, 0);
    sc[cf] = __builtin_amdgcn_mfma_f32_16x16x32_bf16(a1, b1, sc[cf], 0, 0, 0);
  }
  __syncthreads();

  const float scale = 0.125f;
  #pragma unroll
  for (int r = 0; r < 4; ++r){
    const int qrl = 16*w + l4*4 + r;
    float mx = -1e30f;
    #pragma unroll
    for (int cf = 0; cf < 12; ++cf){
      int j  = cf*16 + l15;
      int kj = q0 - 64 + j;
      bool ok = (j >= qrl) && (j <= qrl + 128) && (kj >= 0) && (kj < S);
      float sv = ok ? sc[cf][r]*scale : -1e30f;
      sc[cf][r] = sv;
      mx = fmaxf(mx, sv);
    }
    #pragma unroll
    for (int off = 1; off < 16; off <<= 1) mx = fmaxf(mx, __shfl_xor(mx, off, 64));
    float sm = 0.f;
    #pragma unroll
    for (int cf = 0; cf < 12; ++cf){
      float pv = __expf(sc[cf][r] - mx);
      sc[cf][r] = pv;
      sm += pv;
    }
    #pragma unroll
    for (int off = 1; off < 16; off <<= 1) sm += __shfl_xor(sm, off, 64);
    float inv = 1.0f / sm;
    #pragma unroll
    for (int cf = 0; cf < 12; ++cf) Ps[qrl][cf*16 + l15] = f2bf(sc[cf][r] * inv);
  }
  __syncthreads();

  f32x4 o[4];
  #pragma unroll
  for (int df = 0; df < 4; ++df) o[df] = (f32x4){0.f,0.f,0.f,0.f};
  #pragma unroll
  for (int kk = 0; kk < 6; ++kk){
    short8 a = *(const short8*)&Ps[16*w + l15][kk*32 + ko];
    #pragma unroll
    for (int df = 0; df < 4; ++df){
      short8 b = *(const short8*)&Vt[df*16 + l15][kk*32 + ko];
      o[df] = __builtin_amdgcn_mfma_f32_16x16x32_bf16(a, b, o[df], 0, 0, 0);
    }
  }
  #pragma unroll
  for (int df = 0; df < 4; ++df){
    #pragma unroll
    for (int r = 0; r < 4; ++r){
      attn_out[(size_t)(q0 + 16*w + l4*4 + r)*1024 + h*64 + df*16 + l15] = f2bf(o[df][r]);
    }
  }
}

extern "C" void kernel_launch(void* const* d_in, const int* in_sizes, int n_in,
                              void* d_out, int out_size, void* d_ws, size_t ws_size,
                              hipStream_t stream)
{
  const float* x     = (const float*)d_in[0];
  const float* qkv_w = (const float*)d_in[1];
  const float* out_w = (const float*)d_in[2];
  const float* ln_g  = (const float*)d_in[3];
  const float* ln_b  = (const float*)d_in[4];
  const float* w1    = (const float*)d_in[5];
  const float* b1    = (const float*)d_in[6];
  const float* w2    = (const float*)d_in[7];
  const float* b2    = (const float*)d_in[8];
  float* out_final = (float*)d_out;

  // Layout: first 33.55 MB is buffers all dead by FFN2 -> reused as 4 f32 partials.
  char* p = (char*)d_ws;
  u16* xn_b   = (u16*)p; p += (size_t)2048*1024*2;   // dead after QKV
  u16* qkv_b  = (u16*)p; p += (size_t)2048*3072*2;   // dead after attn
  u16* attn_b = (u16*)p; p += (size_t)2048*1024*2;   // dead after out-proj
  u16* out_b  = (u16*)p; p += (size_t)2048*1024*2;   // dead after FFN1
  u16* qkvw_b = (u16*)p; p += (size_t)3072*1024*2;   // dead after QKV
  u16* outw_b = (u16*)p; p += (size_t)1024*1024*2;   // dead after out-proj
  u16* w1_b   = (u16*)p; p += (size_t)4096*1024*2;
  u16* w2_b   = (u16*)p; p += (size_t)1024*4096*2;
  float* out_f= (float*)p; p += (size_t)2048*1024*4; // live until reduce
  u16* h_b    = (u16*)p; p += (size_t)2048*4096*2;

  float* partials = (float*)xn_b;  // 4 x 2048x1024 f32 = 33.55 MB, exactly covers xn..outw

  // weight conversion
  cvt_bf16<<<3072, 256, 0, stream>>>(qkv_w, qkvw_b, 3072*1024);
  cvt_bf16<<<1024, 256, 0, stream>>>(out_w, outw_b, 1024*1024);
  cvt_bf16<<<4096, 256, 0, stream>>>(w1,    w1_b,   4096*1024);
  cvt_bf16<<<4096, 256, 0, stream>>>(w2,    w2_b,   1024*4096);
  // LayerNorm
  ln_kernel<<<2048, 256, 0, stream>>>(x, ln_g, ln_b, xn_b);
  // QKV projection: [2048,1024] x [3072,1024]^T -> bf16 [2048,3072]  (48x16 = 768 blocks)
  gemm_lds<0><<<dim3(768), 256, 0, stream>>>(xn_b, qkvw_b, nullptr, qkv_b, nullptr, nullptr,
                                             2048, 3072, 1024, 48, 768, 1024);
  // local attention -> bf16 [2048,1024]
  attn_kernel<<<dim3(32,16), 256, 0, stream>>>(qkv_b, attn_b);
  // out projection + residual(x): -> out_f32 + out_bf16  (16x16 = 256 blocks)
  gemm_lds<1><<<dim3(256), 256, 0, stream>>>(attn_b, outw_b, out_f, out_b, nullptr, x,
                                             2048, 1024, 1024, 16, 256, 1024);
  // FFN1 + bias + exact GELU -> h bf16 [2048,4096]  (64x16 = 1024 blocks)
  gemm_lds<2><<<dim3(1024), 256, 0, stream>>>(out_b, w1_b, nullptr, h_b, b1, nullptr,
                                              2048, 4096, 1024, 64, 1024, 1024);
  // FFN2 split-K=4 partials -> f32  (16x16 xy * 4 z = 1024 blocks)
  gemm_lds<4><<<dim3(256, 4), 256, 0, stream>>>(h_b, w2_b, partials, nullptr, nullptr, nullptr,
                                                2048, 1024, 4096, 16, 256, 1024);
  // reduce: out = p0+p1+p2+p3 + b2 + out_f
  reduce_ffn2<<<2048, 256, 0, stream>>>(partials, b2, out_f, out_final);
}